// Round 5
// baseline (404.726 us; speedup 1.0000x reference)
//
#include <hip/hip_runtime.h>
#include <math.h>

// ---------------------------------------------------------------------------
// H=W=512, CELL=8, P=16, NGH=32; nodes = 4*32*32 = 4096 patches of 16x16.
// conv1 3x3 1->40 fp32 VALU; conv2 3x3 40->40 bf16 MFMA (fp32 acc);
// dense1 10240->6 fp32 straight from MFMA accumulators;
// node kernel computes its <=4 incoming edge-MLPs itself (no atomics).
//
// R4 post-mortem: latency-bound, 2 blocks/CU, both pipes <20%. This round:
// LDS 43.5->27.4 KB (XSTRIDE 40, no Cbuf), dense1 from acc regs with
// prep-transposed coalesced weights, B-frag register double-buffering,
// k_edge folded into k_node (grid adjacency is analytic).
// R2 lesson: every register-array access constant-indexed (full unroll).
// ---------------------------------------------------------------------------

typedef __attribute__((ext_vector_type(8))) short short8;
typedef __attribute__((ext_vector_type(4))) float f32x4;

#define XSTRIDE 40          // ushorts per x1 row (= 40 ci exactly, 80 B, 16B-aligned)
#define ZROW    324         // always-zero row (rows 0..323 = 18x18 grid)
#define WCI     64          // wTb ci stride (zero-padded 40->64 for two K=32 steps)
#define WCO     48          // wTb co rows per tap (zero-padded 40->48)

static __device__ __forceinline__ unsigned short f2bf(float x) {
    unsigned int u = __float_as_uint(x);
    u += 0x7FFF + ((u >> 16) & 1);          // round-to-nearest-even
    return (unsigned short)(u >> 16);
}

static __device__ __forceinline__ float diff_round(float x) {
    const float TP = 6.2831853071795864769f;
    return x - sinf(x * TP) / TP;
}

template<int IN, int OUT>
static __device__ __forceinline__ void mlp_layer(const float* in,
                                                 const float* __restrict__ w,
                                                 const float* __restrict__ b,
                                                 float* out, bool do_relu) {
#pragma unroll
    for (int j = 0; j < OUT; ++j) {
        float a = b[j];
#pragma unroll
        for (int i = 0; i < IN; ++i) a = fmaf(in[i], w[i * OUT + j], a);
        out[j] = do_relu ? fmaxf(a, 0.f) : a;
    }
}

// ---------------------------------------------------------------------------
// Prep: (a) w2 [tap][ci][co] fp32 -> wTb [tap][co:48][ci:64] bf16 zero-padded;
//       (b) d1w [pixel*40+co][k] -> d1w2 [pixel][co:48][k:6] fp32 zero-padded
//           (co-major contiguous -> phase-4 reads are lane-coalesced).
// ---------------------------------------------------------------------------
#define NWTB (9 * WCO * WCI)          // 27648
#define ND1W (256 * 48 * 6)           // 73728
__global__ __launch_bounds__(256) void k_prep(const float* __restrict__ w2,
                                              const float* __restrict__ d1w,
                                              unsigned short* __restrict__ wTb,
                                              float* __restrict__ d1w2) {
    const int i = blockIdx.x * 256 + threadIdx.x;
    if (i < NWTB) {
        const int ci  = i & (WCI - 1);
        const int tmp = i >> 6;
        const int co  = tmp % WCO;
        const int tap = tmp / WCO;
        wTb[i] = f2bf((co < 40 && ci < 40) ? w2[(tap * 40 + ci) * 40 + co] : 0.f);
    } else if (i < NWTB + ND1W) {
        const int j   = i - NWTB;
        const int k   = j % 6;
        const int tmp = j / 6;
        const int co  = tmp % 48;
        const int px  = tmp / 48;
        d1w2[j] = (co < 40) ? d1w[(px * 40 + co) * 6 + k] : 0.f;
    }
}

// ---------------------------------------------------------------------------
// Kernel 1: token-build + conv1(fp32) + conv2(bf16 MFMA) + dense1(from acc).
// block = 256 (one thread per pixel), grid = 4096 patches.
// MFMA layouts (HW-verified): A[m=lane&15][k=quad*8+j]; B[k=quad*8+j][n=lane&15];
// C/D col(n)=lane&15, row(m)=quad*4+reg.
// ---------------------------------------------------------------------------
__global__ __launch_bounds__(256, 4) void k_patch(
    const float* __restrict__ img, const float* __restrict__ lab,
    const float* __restrict__ msk,
    const float* __restrict__ w1, const float* __restrict__ b1,
    const unsigned short* __restrict__ wTb, const float* __restrict__ b2,
    const float* __restrict__ d1w2, const float* __restrict__ d1b,
    float* __restrict__ nodes, float* __restrict__ lsv)
{
    __shared__ __align__(16) unsigned short x1[325 * XSTRIDE];  // 26,000 B
    __shared__ float p[18 * 18];
    __shared__ float red[4][2];
    __shared__ float wsum[4][6];

    const int n = blockIdx.x;
    const int t = threadIdx.x;
    const int g = n >> 10, cell = n & 1023;
    const int gi = cell >> 5, gj = cell & 31;
    const int sx = g & 1, sy = g >> 1;           // SHIFTS (0,0),(1,0),(0,1),(1,1)
    const int gx = sx + 2 * gi, gy = sy + 2 * gj;
    const int px0 = gx * 8 - 4, py0 = gy * 8 - 4;
    const float cid = (float)(gx * 64 + gy);

    const int u = t >> 4, v = t & 15;
    const int lane = t & 63, wv = t >> 6;
    const int lane15 = t & 15;                   // MFMA n / m-col index
    const int quad = (t >> 4) & 3;               // lane>>4 within the wave

    // ---- early B-frag prefetch (tap 0): latency hides under phases 0-2 ----
    short8 bcur[3][2];
#pragma unroll
    for (int nt = 0; nt < 3; ++nt)
#pragma unroll
        for (int ks = 0; ks < 2; ++ks)
            bcur[nt][ks] = *(const short8*)(wTb +
                ((0 * WCO + nt * 16 + lane15) * WCI + ks * 32 + quad * 8));

    // ---- phase 0: zero x1 (borders + zero row; interior overwritten) ----
    {
        unsigned int* x1w = (unsigned int*)x1;
        for (int i = t; i < 325 * XSTRIDE / 2; i += 256) x1w[i] = 0u;
        for (int i = t; i < 324; i += 256) p[i] = 0.f;
    }
    __syncthreads();

    // ---- phase 1: token + label stats ----
    const int r = px0 + u, c = py0 + v;
    const bool inr = (r >= 0) && (r < 512) && (c >= 0) && (c < 512);
    const float m  = inr ? msk[r * 512 + c] : -1.0f;
    const float f  = (m == cid) ? 1.f : 0.f;
    const float iv = inr ? img[r * 512 + c] : 0.f;
    const float lv = inr ? lab[r * 512 + c] : 0.f;
    p[(u + 1) * 18 + (v + 1)] = iv * f;

    float sf = f, slf = lv * f;
    for (int off = 32; off; off >>= 1) {
        sf  += __shfl_down(sf,  off);
        slf += __shfl_down(slf, off);
    }
    if (lane == 0) { red[wv][0] = sf; red[wv][1] = slf; }
    __syncthreads();

    // ---- phase 2: conv1 (1->40 fp32) -> relu -> bf16 -> x1 ----
    {
        float nbv[9];
#pragma unroll
        for (int ky = 0; ky < 3; ++ky)
#pragma unroll
            for (int kx = 0; kx < 3; ++kx)
                nbv[ky * 3 + kx] = p[(u + ky) * 18 + (v + kx)];
        float a1[40];
#pragma unroll
        for (int co = 0; co < 40; ++co) a1[co] = b1[co];
#pragma unroll
        for (int k = 0; k < 9; ++k) {
            const float xv = nbv[k];
#pragma unroll
            for (int co = 0; co < 40; ++co)
                a1[co] = fmaf(xv, w1[k * 40 + co], a1[co]);
        }
        const int row = (u + 1) * 18 + (v + 1);
        unsigned int* x1w = (unsigned int*)x1;
#pragma unroll
        for (int cg = 0; cg < 20; ++cg) {
            const unsigned int lo = f2bf(fmaxf(a1[2 * cg], 0.f));
            const unsigned int hi = f2bf(fmaxf(a1[2 * cg + 1], 0.f));
            x1w[row * (XSTRIDE / 2) + cg] = lo | (hi << 16);
        }
    }
    if (t == 0) {
        const float SF = red[0][0] + red[1][0] + red[2][0] + red[3][0];
        const float SL = red[0][1] + red[1][1] + red[2][1] + red[3][1];
        lsv[n] = diff_round(diff_round(SL / (SF + 1e-8f)));
    }
    __syncthreads();

    // ---- phase 3: conv2, per-tap GEMM, B register-double-buffered ----
    float bias[3];
#pragma unroll
    for (int nt = 0; nt < 3; ++nt) {
        const int co = nt * 16 + lane15;
        bias[nt] = (co < 40) ? b2[co] : 0.f;
    }
    f32x4 acc[4][3];
#pragma unroll
    for (int mt = 0; mt < 4; ++mt)
#pragma unroll
        for (int nt = 0; nt < 3; ++nt) {
            acc[mt][nt][0] = bias[nt]; acc[mt][nt][1] = bias[nt];
            acc[mt][nt][2] = bias[nt]; acc[mt][nt][3] = bias[nt];
        }

#pragma unroll
    for (int tap = 0; tap < 9; ++tap) {
        const int ky = tap / 3, kx = tap % 3;
        short8 bnxt[3][2];
        if (tap < 8) {
#pragma unroll
            for (int nt = 0; nt < 3; ++nt)
#pragma unroll
                for (int ks = 0; ks < 2; ++ks)
                    bnxt[nt][ks] = *(const short8*)(wTb +
                        (((tap + 1) * WCO + nt * 16 + lane15) * WCI + ks * 32 + quad * 8));
        }
#pragma unroll
        for (int mt = 0; mt < 4; ++mt) {
            const int arow = (wv * 4 + mt + ky) * 18 + (lane15 + kx);
            const short8 a0 = *(const short8*)(x1 + arow * XSTRIDE + quad * 8);
            // K-step 1: k=32..63 -> quad 0 holds ci 32..39 (real), quads 1-3 zero
            const short8 a1f = (quad == 0)
                ? *(const short8*)(x1 + arow * XSTRIDE + 32)
                : *(const short8*)(x1 + ZROW * XSTRIDE);
#pragma unroll
            for (int nt = 0; nt < 3; ++nt) {
                acc[mt][nt] = __builtin_amdgcn_mfma_f32_16x16x32_bf16(
                    a0, bcur[nt][0], acc[mt][nt], 0, 0, 0);
                acc[mt][nt] = __builtin_amdgcn_mfma_f32_16x16x32_bf16(
                    a1f, bcur[nt][1], acc[mt][nt], 0, 0, 0);
            }
        }
        if (tap < 8) {
#pragma unroll
            for (int nt = 0; nt < 3; ++nt)
#pragma unroll
                for (int ks = 0; ks < 2; ++ks)
                    bcur[nt][ks] = bnxt[nt][ks];
        }
    }

    // ---- phase 4: dense1 directly from accumulators (no Cbuf) ----
    // lane owns (pixel = wv*64+mt*16+quad*4+reg, co = nt*16+lane15);
    // d1w2[pixel][co:48][k:6] is zero for co>=40, so nt=2 tail is branchless.
    float a6[6] = {0.f, 0.f, 0.f, 0.f, 0.f, 0.f};
#pragma unroll
    for (int mt = 0; mt < 4; ++mt)
#pragma unroll
        for (int nt = 0; nt < 3; ++nt) {
            const int co = nt * 16 + lane15;
#pragma unroll
            for (int reg = 0; reg < 4; ++reg) {
                const int pixel = wv * 64 + mt * 16 + quad * 4 + reg;
                const float* __restrict__ dwp = d1w2 + (pixel * 48 + co) * 6;
                const float a = fmaxf(acc[mt][nt][reg], 0.f);
#pragma unroll
                for (int k = 0; k < 6; ++k)
                    a6[k] = fmaf(a, dwp[k], a6[k]);
            }
        }
    for (int off = 32; off; off >>= 1) {
#pragma unroll
        for (int k = 0; k < 6; ++k) a6[k] += __shfl_down(a6[k], off);
    }
    if (lane == 0) {
#pragma unroll
        for (int k = 0; k < 6; ++k) wsum[wv][k] = a6[k];
    }
    __syncthreads();
    if (t < 6) {
        const float s = wsum[0][t] + wsum[1][t] + wsum[2][t] + wsum[3][t] + d1b[t];
        nodes[n * 6 + t] = fmaxf(s, 0.f);
    }
}

// ---------------------------------------------------------------------------
// Kernel 2: per-node fused edge-MLPs (<=4 incoming, analytic grid adjacency)
// + segment sum + node MLP + logits + softmax cross-entropy.
// Incoming senders of node at grid (gx,gy): (gx,gy±1),(gx±1,gy) in-bounds.
// node_id(x,y) = ((x&1)+2*(y&1))*1024 + (x>>1)*32 + (y>>1).
// ---------------------------------------------------------------------------
__global__ __launch_bounds__(256) void k_node(
    const float* __restrict__ nodes, const float* __restrict__ lsv,
    const float* __restrict__ we0, const float* __restrict__ be0,
    const float* __restrict__ we1, const float* __restrict__ be1,
    const float* __restrict__ we2, const float* __restrict__ be2,
    const float* __restrict__ we3, const float* __restrict__ be3,
    const float* __restrict__ wn0, const float* __restrict__ bn0,
    const float* __restrict__ wn1, const float* __restrict__ bn1,
    const float* __restrict__ wn2, const float* __restrict__ bn2,
    const float* __restrict__ wn3, const float* __restrict__ bn3,
    const float* __restrict__ wout, const float* __restrict__ bout,
    float* __restrict__ out, int N)
{
    const int n = blockIdx.x * 256 + threadIdx.x;
    if (n >= N) return;
    const int g = n >> 10, cell = n & 1023;
    const int gi = cell >> 5, gj = cell & 31;
    const int gx = (g & 1) + 2 * gi, gy = (g >> 1) + 2 * gj;

    float self6[6];
#pragma unroll
    for (int i = 0; i < 6; ++i) self6[i] = nodes[n * 6 + i];

    float agg[10] = {0.f,0.f,0.f,0.f,0.f,0.f,0.f,0.f,0.f,0.f};
    const int DX[4] = {0, 0, -1, 1};
    const int DY[4] = {-1, 1, 0, 0};
#pragma unroll
    for (int d = 0; d < 4; ++d) {
        const int x = gx + DX[d], y = gy + DY[d];
        if (x >= 0 && x < 64 && y >= 0 && y < 64) {
            const int mid = ((x & 1) + 2 * (y & 1)) * 1024 + (x >> 1) * 32 + (y >> 1);
            float in13[13];
#pragma unroll
            for (int i = 0; i < 6; ++i) in13[i] = nodes[mid * 6 + i];  // sender
#pragma unroll
            for (int i = 0; i < 6; ++i) in13[6 + i] = self6[i];        // receiver
            in13[12] = 1.f;
            float h0[5], h1[5], h2[5], o[10];
            mlp_layer<13, 5>(in13, we0, be0, h0, true);
            mlp_layer<5, 5>(h0, we1, be1, h1, true);
            mlp_layer<5, 5>(h1, we2, be2, h2, true);
            mlp_layer<5, 10>(h2, we3, be3, o, false);
#pragma unroll
            for (int j = 0; j < 10; ++j) agg[j] += o[j];
        }
    }

    float in17[17];
#pragma unroll
    for (int i = 0; i < 6; ++i)  in17[i]     = self6[i];
#pragma unroll
    for (int i = 0; i < 10; ++i) in17[6 + i] = agg[i];
    in17[16] = 1.f;
    float h0[5], h1[5], h2[5], o[10];
    mlp_layer<17, 5>(in17, wn0, bn0, h0, true);
    mlp_layer<5, 5>(h0, wn1, bn1, h1, true);
    mlp_layer<5, 5>(h1, wn2, bn2, h2, true);
    mlp_layer<5, 10>(h2, wn3, bn3, o, false);

    float l0 = bout[0], l1 = bout[1];
#pragma unroll
    for (int i = 0; i < 10; ++i) {
        l0 = fmaf(o[i], wout[i * 2 + 0], l0);
        l1 = fmaf(o[i], wout[i * 2 + 1], l1);
    }
    const float mx  = fmaxf(l0, l1);
    const float e0  = expf(l0 - mx), e1 = expf(l1 - mx);
    const float lse = mx + logf(e0 + e1);
    const float sv  = lsv[n];
    out[n] = -((1.f - sv) * (l0 - lse) + sv * (l1 - lse));
}

// ---------------------------------------------------------------------------
extern "C" void kernel_launch(void* const* d_in, const int* in_sizes, int n_in,
                              void* d_out, int out_size, void* d_ws, size_t ws_size,
                              hipStream_t stream) {
    (void)n_in; (void)ws_size; (void)in_sizes;
    const float* img = (const float*)d_in[0];
    const float* lab = (const float*)d_in[1];
    const float* msk = (const float*)d_in[2];
    const float* w1  = (const float*)d_in[3];
    const float* b1  = (const float*)d_in[4];
    const float* w2  = (const float*)d_in[5];
    const float* b2  = (const float*)d_in[6];
    const float* d1w = (const float*)d_in[7];
    const float* d1b = (const float*)d_in[8];
    const float* we0 = (const float*)d_in[9],  *be0 = (const float*)d_in[10];
    const float* we1 = (const float*)d_in[11], *be1 = (const float*)d_in[12];
    const float* we2 = (const float*)d_in[13], *be2 = (const float*)d_in[14];
    const float* we3 = (const float*)d_in[15], *be3 = (const float*)d_in[16];
    const float* wn0 = (const float*)d_in[17], *bn0 = (const float*)d_in[18];
    const float* wn1 = (const float*)d_in[19], *bn1 = (const float*)d_in[20];
    const float* wn2 = (const float*)d_in[21], *bn2 = (const float*)d_in[22];
    const float* wn3 = (const float*)d_in[23], *bn3 = (const float*)d_in[24];
    const float* wout = (const float*)d_in[25], *bout = (const float*)d_in[26];
    const int N = out_size;              // 4096 nodes

    float* ws    = (float*)d_ws;
    float* nodes = ws;                                   // N*6
    float* lsvb  = ws + (size_t)N * 6;                   // N
    unsigned short* wTb = (unsigned short*)(ws + (size_t)N * 7);   // 27,648 bf16
    float* d1w2  = ws + (size_t)N * 7 + NWTB / 2;        // 73,728 fp32
    float* out   = (float*)d_out;

    const int prep_n = NWTB + ND1W;
    k_prep<<<(prep_n + 255) / 256, 256, 0, stream>>>(w2, d1w, wTb, d1w2);
    k_patch<<<N, 256, 0, stream>>>(img, lab, msk, w1, b1, wTb, b2, d1w2, d1b,
                                   nodes, lsvb);
    k_node<<<(N + 255) / 256, 256, 0, stream>>>(nodes, lsvb,
                                                we0, be0, we1, be1, we2, be2,
                                                we3, be3,
                                                wn0, bn0, wn1, bn1, wn2, bn2,
                                                wn3, bn3, wout, bout, out, N);
}

// Round 6
// 309.857 us; speedup vs baseline: 1.3062x; 1.3062x over previous
//
#include <hip/hip_runtime.h>
#include <math.h>

// ---------------------------------------------------------------------------
// H=W=512, CELL=8, P=16, NGH=32; nodes = 4*32*32 = 4096 patches of 16x16.
// conv1 3x3 1->40 fp32 VALU; conv2 3x3 40->40 bf16 MFMA (fp32 acc);
// dense1 10240->6 fp32 straight from MFMA accumulators;
// node kernel computes its <=4 incoming edge-MLPs itself (no atomics).
//
// R5 post-mortem: __launch_bounds__(256,4) capped VGPRs at 128 < the ~140
// live set (acc 48 + B-dbuf 48 + addressing) -> forced spill: VGPR=64,
// WRITE_SIZE=548 MB, HBM 3.1 TB/s, 295 us. Fix: back to (256,2) (256-VGPR
// budget) — LDS at 27.6 KB still allows 3+ blocks/CU at ~150 VGPRs.
// R2 lesson stands: every register-array access constant-indexed.
// ---------------------------------------------------------------------------

typedef __attribute__((ext_vector_type(8))) short short8;
typedef __attribute__((ext_vector_type(4))) float f32x4;

#define XSTRIDE 40          // ushorts per x1 row (= 40 ci exactly, 80 B, 16B-aligned)
#define ZROW    324         // always-zero row (rows 0..323 = 18x18 grid)
#define WCI     64          // wTb ci stride (zero-padded 40->64 for two K=32 steps)
#define WCO     48          // wTb co rows per tap (zero-padded 40->48)

static __device__ __forceinline__ unsigned short f2bf(float x) {
    unsigned int u = __float_as_uint(x);
    u += 0x7FFF + ((u >> 16) & 1);          // round-to-nearest-even
    return (unsigned short)(u >> 16);
}

static __device__ __forceinline__ float diff_round(float x) {
    const float TP = 6.2831853071795864769f;
    return x - sinf(x * TP) / TP;
}

template<int IN, int OUT>
static __device__ __forceinline__ void mlp_layer(const float* in,
                                                 const float* __restrict__ w,
                                                 const float* __restrict__ b,
                                                 float* out, bool do_relu) {
#pragma unroll
    for (int j = 0; j < OUT; ++j) {
        float a = b[j];
#pragma unroll
        for (int i = 0; i < IN; ++i) a = fmaf(in[i], w[i * OUT + j], a);
        out[j] = do_relu ? fmaxf(a, 0.f) : a;
    }
}

// ---------------------------------------------------------------------------
// Prep: (a) w2 [tap][ci][co] fp32 -> wTb [tap][co:48][ci:64] bf16 zero-padded;
//       (b) d1w [pixel*40+co][k] -> d1w2 [pixel][co:48][k:6] fp32 zero-padded
//           (co-major contiguous -> phase-4 reads are lane-coalesced).
// ---------------------------------------------------------------------------
#define NWTB (9 * WCO * WCI)          // 27648
#define ND1W (256 * 48 * 6)           // 73728
__global__ __launch_bounds__(256) void k_prep(const float* __restrict__ w2,
                                              const float* __restrict__ d1w,
                                              unsigned short* __restrict__ wTb,
                                              float* __restrict__ d1w2) {
    const int i = blockIdx.x * 256 + threadIdx.x;
    if (i < NWTB) {
        const int ci  = i & (WCI - 1);
        const int tmp = i >> 6;
        const int co  = tmp % WCO;
        const int tap = tmp / WCO;
        wTb[i] = f2bf((co < 40 && ci < 40) ? w2[(tap * 40 + ci) * 40 + co] : 0.f);
    } else if (i < NWTB + ND1W) {
        const int j   = i - NWTB;
        const int k   = j % 6;
        const int tmp = j / 6;
        const int co  = tmp % 48;
        const int px  = tmp / 48;
        d1w2[j] = (co < 40) ? d1w[(px * 40 + co) * 6 + k] : 0.f;
    }
}

// ---------------------------------------------------------------------------
// Kernel 1: token-build + conv1(fp32) + conv2(bf16 MFMA) + dense1(from acc).
// block = 256 (one thread per pixel), grid = 4096 patches.
// MFMA layouts (HW-verified): A[m=lane&15][k=quad*8+j]; B[k=quad*8+j][n=lane&15];
// C/D col(n)=lane&15, row(m)=quad*4+reg.
// __launch_bounds__(256,2): 256-VGPR budget. (256,4)'s 128 cap forced the
// accumulator spill seen in R5 (WRITE_SIZE 548 MB). Do not tighten.
// ---------------------------------------------------------------------------
__global__ __launch_bounds__(256, 2) void k_patch(
    const float* __restrict__ img, const float* __restrict__ lab,
    const float* __restrict__ msk,
    const float* __restrict__ w1, const float* __restrict__ b1,
    const unsigned short* __restrict__ wTb, const float* __restrict__ b2,
    const float* __restrict__ d1w2, const float* __restrict__ d1b,
    float* __restrict__ nodes, float* __restrict__ lsv)
{
    __shared__ __align__(16) unsigned short x1[325 * XSTRIDE];  // 26,000 B
    __shared__ float p[18 * 18];
    __shared__ float red[4][2];
    __shared__ float wsum[4][6];

    const int n = blockIdx.x;
    const int t = threadIdx.x;
    const int g = n >> 10, cell = n & 1023;
    const int gi = cell >> 5, gj = cell & 31;
    const int sx = g & 1, sy = g >> 1;           // SHIFTS (0,0),(1,0),(0,1),(1,1)
    const int gx = sx + 2 * gi, gy = sy + 2 * gj;
    const int px0 = gx * 8 - 4, py0 = gy * 8 - 4;
    const float cid = (float)(gx * 64 + gy);

    const int u = t >> 4, v = t & 15;
    const int lane = t & 63, wv = t >> 6;
    const int lane15 = t & 15;                   // MFMA n / m-col index
    const int quad = (t >> 4) & 3;               // lane>>4 within the wave

    // ---- early B-frag prefetch (tap 0): latency hides under phases 0-2 ----
    short8 bcur[3][2];
#pragma unroll
    for (int nt = 0; nt < 3; ++nt)
#pragma unroll
        for (int ks = 0; ks < 2; ++ks)
            bcur[nt][ks] = *(const short8*)(wTb +
                ((0 * WCO + nt * 16 + lane15) * WCI + ks * 32 + quad * 8));

    // ---- phase 0: zero x1 (borders + zero row; interior overwritten) ----
    {
        unsigned int* x1w = (unsigned int*)x1;
        for (int i = t; i < 325 * XSTRIDE / 2; i += 256) x1w[i] = 0u;
        for (int i = t; i < 324; i += 256) p[i] = 0.f;
    }
    __syncthreads();

    // ---- phase 1: token + label stats ----
    const int r = px0 + u, c = py0 + v;
    const bool inr = (r >= 0) && (r < 512) && (c >= 0) && (c < 512);
    const float m  = inr ? msk[r * 512 + c] : -1.0f;
    const float f  = (m == cid) ? 1.f : 0.f;
    const float iv = inr ? img[r * 512 + c] : 0.f;
    const float lv = inr ? lab[r * 512 + c] : 0.f;
    p[(u + 1) * 18 + (v + 1)] = iv * f;

    float sf = f, slf = lv * f;
    for (int off = 32; off; off >>= 1) {
        sf  += __shfl_down(sf,  off);
        slf += __shfl_down(slf, off);
    }
    if (lane == 0) { red[wv][0] = sf; red[wv][1] = slf; }
    __syncthreads();

    // ---- phase 2: conv1 (1->40 fp32) -> relu -> bf16 -> x1 ----
    {
        float nbv[9];
#pragma unroll
        for (int ky = 0; ky < 3; ++ky)
#pragma unroll
            for (int kx = 0; kx < 3; ++kx)
                nbv[ky * 3 + kx] = p[(u + ky) * 18 + (v + kx)];
        float a1[40];
#pragma unroll
        for (int co = 0; co < 40; ++co) a1[co] = b1[co];
#pragma unroll
        for (int k = 0; k < 9; ++k) {
            const float xv = nbv[k];
#pragma unroll
            for (int co = 0; co < 40; ++co)
                a1[co] = fmaf(xv, w1[k * 40 + co], a1[co]);
        }
        const int row = (u + 1) * 18 + (v + 1);
        unsigned int* x1w = (unsigned int*)x1;
#pragma unroll
        for (int cg = 0; cg < 20; ++cg) {
            const unsigned int lo = f2bf(fmaxf(a1[2 * cg], 0.f));
            const unsigned int hi = f2bf(fmaxf(a1[2 * cg + 1], 0.f));
            x1w[row * (XSTRIDE / 2) + cg] = lo | (hi << 16);
        }
    }
    if (t == 0) {
        const float SF = red[0][0] + red[1][0] + red[2][0] + red[3][0];
        const float SL = red[0][1] + red[1][1] + red[2][1] + red[3][1];
        lsv[n] = diff_round(diff_round(SL / (SF + 1e-8f)));
    }
    __syncthreads();

    // ---- phase 3: conv2, per-tap GEMM, B register-double-buffered ----
    float bias[3];
#pragma unroll
    for (int nt = 0; nt < 3; ++nt) {
        const int co = nt * 16 + lane15;
        bias[nt] = (co < 40) ? b2[co] : 0.f;
    }
    f32x4 acc[4][3];
#pragma unroll
    for (int mt = 0; mt < 4; ++mt)
#pragma unroll
        for (int nt = 0; nt < 3; ++nt) {
            acc[mt][nt][0] = bias[nt]; acc[mt][nt][1] = bias[nt];
            acc[mt][nt][2] = bias[nt]; acc[mt][nt][3] = bias[nt];
        }

#pragma unroll
    for (int tap = 0; tap < 9; ++tap) {
        const int ky = tap / 3, kx = tap % 3;
        short8 bnxt[3][2];
        if (tap < 8) {
#pragma unroll
            for (int nt = 0; nt < 3; ++nt)
#pragma unroll
                for (int ks = 0; ks < 2; ++ks)
                    bnxt[nt][ks] = *(const short8*)(wTb +
                        (((tap + 1) * WCO + nt * 16 + lane15) * WCI + ks * 32 + quad * 8));
        }
#pragma unroll
        for (int mt = 0; mt < 4; ++mt) {
            const int arow = (wv * 4 + mt + ky) * 18 + (lane15 + kx);
            const short8 a0 = *(const short8*)(x1 + arow * XSTRIDE + quad * 8);
            // K-step 1: k=32..63 -> quad 0 holds ci 32..39 (real), quads 1-3 zero
            const short8 a1f = (quad == 0)
                ? *(const short8*)(x1 + arow * XSTRIDE + 32)
                : *(const short8*)(x1 + ZROW * XSTRIDE);
#pragma unroll
            for (int nt = 0; nt < 3; ++nt) {
                acc[mt][nt] = __builtin_amdgcn_mfma_f32_16x16x32_bf16(
                    a0, bcur[nt][0], acc[mt][nt], 0, 0, 0);
                acc[mt][nt] = __builtin_amdgcn_mfma_f32_16x16x32_bf16(
                    a1f, bcur[nt][1], acc[mt][nt], 0, 0, 0);
            }
        }
        if (tap < 8) {
#pragma unroll
            for (int nt = 0; nt < 3; ++nt)
#pragma unroll
                for (int ks = 0; ks < 2; ++ks)
                    bcur[nt][ks] = bnxt[nt][ks];
        }
    }

    // ---- phase 4: dense1 directly from accumulators (no Cbuf) ----
    // lane owns (pixel = wv*64+mt*16+quad*4+reg, co = nt*16+lane15);
    // d1w2[pixel][co:48][k:6] is zero for co>=40, so nt=2 tail is branchless.
    float a6[6] = {0.f, 0.f, 0.f, 0.f, 0.f, 0.f};
#pragma unroll
    for (int mt = 0; mt < 4; ++mt)
#pragma unroll
        for (int nt = 0; nt < 3; ++nt) {
            const int co = nt * 16 + lane15;
#pragma unroll
            for (int reg = 0; reg < 4; ++reg) {
                const int pixel = wv * 64 + mt * 16 + quad * 4 + reg;
                const float* __restrict__ dwp = d1w2 + (pixel * 48 + co) * 6;
                const float a = fmaxf(acc[mt][nt][reg], 0.f);
#pragma unroll
                for (int k = 0; k < 6; ++k)
                    a6[k] = fmaf(a, dwp[k], a6[k]);
            }
        }
    for (int off = 32; off; off >>= 1) {
#pragma unroll
        for (int k = 0; k < 6; ++k) a6[k] += __shfl_down(a6[k], off);
    }
    if (lane == 0) {
#pragma unroll
        for (int k = 0; k < 6; ++k) wsum[wv][k] = a6[k];
    }
    __syncthreads();
    if (t < 6) {
        const float s = wsum[0][t] + wsum[1][t] + wsum[2][t] + wsum[3][t] + d1b[t];
        nodes[n * 6 + t] = fmaxf(s, 0.f);
    }
}

// ---------------------------------------------------------------------------
// Kernel 2: per-node fused edge-MLPs (<=4 incoming, analytic grid adjacency)
// + segment sum + node MLP + logits + softmax cross-entropy.
// Incoming senders of node at grid (gx,gy): (gx,gy±1),(gx±1,gy) in-bounds.
// node_id(x,y) = ((x&1)+2*(y&1))*1024 + (x>>1)*32 + (y>>1).
// ---------------------------------------------------------------------------
__global__ __launch_bounds__(256) void k_node(
    const float* __restrict__ nodes, const float* __restrict__ lsv,
    const float* __restrict__ we0, const float* __restrict__ be0,
    const float* __restrict__ we1, const float* __restrict__ be1,
    const float* __restrict__ we2, const float* __restrict__ be2,
    const float* __restrict__ we3, const float* __restrict__ be3,
    const float* __restrict__ wn0, const float* __restrict__ bn0,
    const float* __restrict__ wn1, const float* __restrict__ bn1,
    const float* __restrict__ wn2, const float* __restrict__ bn2,
    const float* __restrict__ wn3, const float* __restrict__ bn3,
    const float* __restrict__ wout, const float* __restrict__ bout,
    float* __restrict__ out, int N)
{
    const int n = blockIdx.x * 256 + threadIdx.x;
    if (n >= N) return;
    const int g = n >> 10, cell = n & 1023;
    const int gi = cell >> 5, gj = cell & 31;
    const int gx = (g & 1) + 2 * gi, gy = (g >> 1) + 2 * gj;

    float self6[6];
#pragma unroll
    for (int i = 0; i < 6; ++i) self6[i] = nodes[n * 6 + i];

    float agg[10] = {0.f,0.f,0.f,0.f,0.f,0.f,0.f,0.f,0.f,0.f};
    const int DX[4] = {0, 0, -1, 1};
    const int DY[4] = {-1, 1, 0, 0};
#pragma unroll
    for (int d = 0; d < 4; ++d) {
        const int x = gx + DX[d], y = gy + DY[d];
        if (x >= 0 && x < 64 && y >= 0 && y < 64) {
            const int mid = ((x & 1) + 2 * (y & 1)) * 1024 + (x >> 1) * 32 + (y >> 1);
            float in13[13];
#pragma unroll
            for (int i = 0; i < 6; ++i) in13[i] = nodes[mid * 6 + i];  // sender
#pragma unroll
            for (int i = 0; i < 6; ++i) in13[6 + i] = self6[i];        // receiver
            in13[12] = 1.f;
            float h0[5], h1[5], h2[5], o[10];
            mlp_layer<13, 5>(in13, we0, be0, h0, true);
            mlp_layer<5, 5>(h0, we1, be1, h1, true);
            mlp_layer<5, 5>(h1, we2, be2, h2, true);
            mlp_layer<5, 10>(h2, we3, be3, o, false);
#pragma unroll
            for (int j = 0; j < 10; ++j) agg[j] += o[j];
        }
    }

    float in17[17];
#pragma unroll
    for (int i = 0; i < 6; ++i)  in17[i]     = self6[i];
#pragma unroll
    for (int i = 0; i < 10; ++i) in17[6 + i] = agg[i];
    in17[16] = 1.f;
    float h0[5], h1[5], h2[5], o[10];
    mlp_layer<17, 5>(in17, wn0, bn0, h0, true);
    mlp_layer<5, 5>(h0, wn1, bn1, h1, true);
    mlp_layer<5, 5>(h1, wn2, bn2, h2, true);
    mlp_layer<5, 10>(h2, wn3, bn3, o, false);

    float l0 = bout[0], l1 = bout[1];
#pragma unroll
    for (int i = 0; i < 10; ++i) {
        l0 = fmaf(o[i], wout[i * 2 + 0], l0);
        l1 = fmaf(o[i], wout[i * 2 + 1], l1);
    }
    const float mx  = fmaxf(l0, l1);
    const float e0  = expf(l0 - mx), e1 = expf(l1 - mx);
    const float lse = mx + logf(e0 + e1);
    const float sv  = lsv[n];
    out[n] = -((1.f - sv) * (l0 - lse) + sv * (l1 - lse));
}

// ---------------------------------------------------------------------------
extern "C" void kernel_launch(void* const* d_in, const int* in_sizes, int n_in,
                              void* d_out, int out_size, void* d_ws, size_t ws_size,
                              hipStream_t stream) {
    (void)n_in; (void)ws_size; (void)in_sizes;
    const float* img = (const float*)d_in[0];
    const float* lab = (const float*)d_in[1];
    const float* msk = (const float*)d_in[2];
    const float* w1  = (const float*)d_in[3];
    const float* b1  = (const float*)d_in[4];
    const float* w2  = (const float*)d_in[5];
    const float* b2  = (const float*)d_in[6];
    const float* d1w = (const float*)d_in[7];
    const float* d1b = (const float*)d_in[8];
    const float* we0 = (const float*)d_in[9],  *be0 = (const float*)d_in[10];
    const float* we1 = (const float*)d_in[11], *be1 = (const float*)d_in[12];
    const float* we2 = (const float*)d_in[13], *be2 = (const float*)d_in[14];
    const float* we3 = (const float*)d_in[15], *be3 = (const float*)d_in[16];
    const float* wn0 = (const float*)d_in[17], *bn0 = (const float*)d_in[18];
    const float* wn1 = (const float*)d_in[19], *bn1 = (const float*)d_in[20];
    const float* wn2 = (const float*)d_in[21], *bn2 = (const float*)d_in[22];
    const float* wn3 = (const float*)d_in[23], *bn3 = (const float*)d_in[24];
    const float* wout = (const float*)d_in[25], *bout = (const float*)d_in[26];
    const int N = out_size;              // 4096 nodes

    float* ws    = (float*)d_ws;
    float* nodes = ws;                                   // N*6
    float* lsvb  = ws + (size_t)N * 6;                   // N
    unsigned short* wTb = (unsigned short*)(ws + (size_t)N * 7);   // 27,648 bf16
    float* d1w2  = ws + (size_t)N * 7 + NWTB / 2;        // 73,728 fp32
    float* out   = (float*)d_out;

    const int prep_n = NWTB + ND1W;
    k_prep<<<(prep_n + 255) / 256, 256, 0, stream>>>(w2, d1w, wTb, d1w2);
    k_patch<<<N, 256, 0, stream>>>(img, lab, msk, w1, b1, wTb, b2, d1w2, d1b,
                                   nodes, lsvb);
    k_node<<<(N + 255) / 256, 256, 0, stream>>>(nodes, lsvb,
                                                we0, be0, we1, be1, we2, be2,
                                                we3, be3,
                                                wn0, bn0, wn1, bn1, wn2, bn2,
                                                wn3, bn3, wout, bout, out, N);
}

// Round 7
// 284.173 us; speedup vs baseline: 1.4242x; 1.0904x over previous
//
#include <hip/hip_runtime.h>
#include <math.h>

// ---------------------------------------------------------------------------
// H=W=512, CELL=8, P=16, NGH=32; 4096 patches of 16x16, one block per patch.
// conv1 3x3 1->40 fp32 VALU; conv2 3x3 40->40 bf16 MFMA; dense1 from acc regs.
//
// R6 post-mortem: latency-bound at ~2 blocks/CU (140 total regs), 3.1K VALU
// inst/wave, MfmaUtil 11.7 / VALUBusy 20.8 / Occ 22.5. R7 restructure:
//  - 512-thread blocks (8 waves/patch): acc 48->24 regs, conv1 split over
//    2 channel-halves, phase-4 halved -> live set ~95 regs.
//  - __launch_bounds__(512,4): 128-reg cap -> 2 blocks/CU (50% occ). R5's
//    spill was ~140 live vs 128 cap; here ~95 live. Tripwire: WRITE_SIZE.
//  - Tail-packed K: ci 32..39 of 4 taps share one K=32 MFMA step (per-quad
//    A addresses + repacked B tail) -> 12 MFMAs/(mt,nt) instead of 18.
//  - Barriers 4->3: p unpadded 16x16 (borders via cndmask), x1 zeroing
//    borders-only, entry-issued global loads.
// R2 lesson stands: every register-array access constant-indexed.
// MFMA layouts (HW-verified): A[m=lane&15][k=quad*8+j]; B[k=quad*8+j][n=lane&15];
// C/D col(n)=lane&15, row(m)=quad*4+reg.
// ---------------------------------------------------------------------------

typedef __attribute__((ext_vector_type(8))) short short8;
typedef __attribute__((ext_vector_type(4))) float f32x4;

#define ZROW    324                  // always-zero x1 row (rows 0..323 = 18x18)
#define NWTB    (9 * 48 * 32)        // 13824: main B  [tap][co:48][ci:32]
#define NTAIL   (3 * 48 * 32)        // 4608:  tail B  [s][co:48][k:32]
#define ND1W    (256 * 48 * 6)       // 73728: dense1  [pixel][co:48][k:6]

static __device__ __forceinline__ unsigned short f2bf(float x) {
    unsigned int u = __float_as_uint(x);
    u += 0x7FFF + ((u >> 16) & 1);
    return (unsigned short)(u >> 16);
}

static __device__ __forceinline__ float diff_round(float x) {
    const float TP = 6.2831853071795864769f;
    return x - sinf(x * TP) / TP;
}

template<int IN, int OUT>
static __device__ __forceinline__ void mlp_layer(const float* in,
                                                 const float* __restrict__ w,
                                                 const float* __restrict__ b,
                                                 float* out, bool do_relu) {
#pragma unroll
    for (int j = 0; j < OUT; ++j) {
        float a = b[j];
#pragma unroll
        for (int i = 0; i < IN; ++i) a = fmaf(in[i], w[i * OUT + j], a);
        out[j] = do_relu ? fmaxf(a, 0.f) : a;
    }
}

// ---------------------------------------------------------------------------
// Prep: main B, tail B, dense1 weights, all zero-padded/reordered.
// tail: wTbT[s][co][k], k=quad*8+j -> tap=s*4+quad, ci=32+j (tap>=9 -> 0).
// ---------------------------------------------------------------------------
__global__ __launch_bounds__(256) void k_prep(const float* __restrict__ w2,
                                              const float* __restrict__ d1w,
                                              unsigned short* __restrict__ wTb,
                                              unsigned short* __restrict__ wTbT,
                                              float* __restrict__ d1w2) {
    const int i = blockIdx.x * 256 + threadIdx.x;
    if (i < NWTB) {
        const int ci  = i & 31;
        const int co  = (i >> 5) % 48;
        const int tap = (i >> 5) / 48;
        wTb[i] = f2bf((co < 40) ? w2[(tap * 40 + ci) * 40 + co] : 0.f);
    } else if (i < NWTB + NTAIL) {
        const int j   = i - NWTB;
        const int k   = j & 31;
        const int co  = (j >> 5) % 48;
        const int s   = (j >> 5) / 48;
        const int tap = s * 4 + (k >> 3);
        const int ci  = 32 + (k & 7);
        wTbT[j] = f2bf((tap < 9 && co < 40) ? w2[(tap * 40 + ci) * 40 + co] : 0.f);
    } else if (i < NWTB + NTAIL + ND1W) {
        const int j   = i - NWTB - NTAIL;
        const int k   = j % 6;
        const int tmp = j / 6;
        const int co  = tmp % 48;
        const int px  = tmp / 48;
        d1w2[j] = (co < 40) ? d1w[(px * 40 + co) * 6 + k] : 0.f;
    }
}

// ---------------------------------------------------------------------------
// Kernel 1: 512 threads/block, one block per patch.
// Threads: ph = t>>8 (channel half), pix = t&255, u=pix>>4, v=pix&15.
// Wave wv (0..7) owns image rows u = wv*2, wv*2+1 in the MFMA phase.
// ---------------------------------------------------------------------------
__global__ __launch_bounds__(512, 4) void k_patch(
    const float* __restrict__ img, const float* __restrict__ lab,
    const float* __restrict__ msk,
    const float* __restrict__ w1, const float* __restrict__ b1,
    const unsigned short* __restrict__ wTb,
    const unsigned short* __restrict__ wTbT,
    const float* __restrict__ b2,
    const float* __restrict__ d1w2, const float* __restrict__ d1b,
    float* __restrict__ nodes, float* __restrict__ lsv)
{
    __shared__ __align__(16) unsigned short x1[325 * 40];   // 26,000 B
    __shared__ float p[256];
    __shared__ float red[4][2];
    __shared__ float wsum[8][6];

    const int n = blockIdx.x;
    const int t = threadIdx.x;
    const int g = n >> 10, cell = n & 1023;
    const int gi = cell >> 5, gj = cell & 31;
    const int sx = g & 1, sy = g >> 1;           // SHIFTS (0,0),(1,0),(0,1),(1,1)
    const int gx = sx + 2 * gi, gy = sy + 2 * gj;
    const int px0 = gx * 8 - 4, py0 = gy * 8 - 4;
    const float cid = (float)(gx * 64 + gy);

    const int ph = t >> 8, pix = t & 255;
    const int u = pix >> 4, v = pix & 15;
    const int lane = t & 63, wv = t >> 6;
    const int lane15 = t & 15, quad = (t >> 4) & 3;

    // ---- entry: issue global loads immediately (ph==0 half only) ----
    float m = -1.f, iv = 0.f, lv = 0.f;
    if (ph == 0) {
        const int r = px0 + u, c = py0 + v;
        if (r >= 0 && r < 512 && c >= 0 && c < 512) {
            m  = msk[r * 512 + c];
            iv = img[r * 512 + c];
            lv = lab[r * 512 + c];
        }
    }

    // ---- zero x1 borders + ZROW only (69 cells * 20 dwords = 1380) ----
    {
        unsigned int* x1w = (unsigned int*)x1;
        for (int i = t; i < 69 * 20; i += 512) {
            const int cellI = i / 20, d = i - cellI * 20;
            int cr;
            if      (cellI < 18) cr = cellI;                    // row 0
            else if (cellI < 36) cr = cellI + 288;              // row 17
            else if (cellI < 52) cr = (cellI - 35) * 18;        // col 0, rows 1..16
            else if (cellI < 68) cr = (cellI - 51) * 18 + 17;   // col 17
            else                 cr = ZROW;
            x1w[cr * 20 + d] = 0u;
        }
    }

    // ---- token + label stats (ph==0: waves 0..3) ----
    const float f = (m == cid) ? 1.f : 0.f;
    if (ph == 0) {
        p[pix] = iv * f;
        float sf = f, slf = lv * f;
        for (int off = 32; off; off >>= 1) {
            sf  += __shfl_down(sf,  off);
            slf += __shfl_down(slf, off);
        }
        if (lane == 0) { red[wv][0] = sf; red[wv][1] = slf; }
    }
    __syncthreads();                                   // B1: p, red, x1 borders

    if (t == 0) {
        const float SF = red[0][0] + red[1][0] + red[2][0] + red[3][0];
        const float SL = red[0][1] + red[1][1] + red[2][1] + red[3][1];
        lsv[n] = diff_round(diff_round(SL / (SF + 1e-8f)));
    }

    // ---- conv1: each thread does its pixel x its 20-channel half ----
    {
        float nbv[9];
#pragma unroll
        for (int ky = 0; ky < 3; ++ky)
#pragma unroll
            for (int kx = 0; kx < 3; ++kx) {
                const int uy = u + ky - 1, vx = v + kx - 1;
                const bool ok = (uy >= 0) && (uy < 16) && (vx >= 0) && (vx < 16);
                nbv[ky * 3 + kx] = ok ? p[uy * 16 + vx] : 0.f;
            }
        float a1[20];
#pragma unroll
        for (int cc = 0; cc < 20; ++cc) a1[cc] = b1[ph * 20 + cc];
#pragma unroll
        for (int k = 0; k < 9; ++k) {
            const float xv = nbv[k];
#pragma unroll
            for (int cc = 0; cc < 20; ++cc)
                a1[cc] = fmaf(xv, w1[k * 40 + ph * 20 + cc], a1[cc]);
        }
        const int row = (u + 1) * 18 + (v + 1);
        unsigned int* x1w = (unsigned int*)x1;
#pragma unroll
        for (int cg = 0; cg < 10; ++cg) {
            const unsigned int lo = f2bf(fmaxf(a1[2 * cg], 0.f));
            const unsigned int hi = f2bf(fmaxf(a1[2 * cg + 1], 0.f));
            x1w[row * 20 + ph * 10 + cg] = lo | (hi << 16);
        }
    }
    __syncthreads();                                   // B2: x1 ready

    // ---- conv2: 9 main K-steps (ci 0..31) + 3 tail K-steps (ci 32..39) ----
    float bias[3];
#pragma unroll
    for (int nt = 0; nt < 3; ++nt) {
        const int co = nt * 16 + lane15;
        bias[nt] = (co < 40) ? b2[co] : 0.f;
    }
    f32x4 acc[2][3];
#pragma unroll
    for (int mt = 0; mt < 2; ++mt)
#pragma unroll
        for (int nt = 0; nt < 3; ++nt) {
            acc[mt][nt][0] = bias[nt]; acc[mt][nt][1] = bias[nt];
            acc[mt][nt][2] = bias[nt]; acc[mt][nt][3] = bias[nt];
        }

#pragma unroll
    for (int tap = 0; tap < 9; ++tap) {
        const int ky = tap / 3, kx = tap % 3;
        short8 bf[3];
#pragma unroll
        for (int nt = 0; nt < 3; ++nt)
            bf[nt] = *(const short8*)(wTb + (tap * 48 + nt * 16 + lane15) * 32 + quad * 8);
#pragma unroll
        for (int mt = 0; mt < 2; ++mt) {
            const int arow = (wv * 2 + mt + ky) * 18 + (lane15 + kx);
            const short8 a0 = *(const short8*)(x1 + arow * 40 + quad * 8);
#pragma unroll
            for (int nt = 0; nt < 3; ++nt)
                acc[mt][nt] = __builtin_amdgcn_mfma_f32_16x16x32_bf16(
                    a0, bf[nt], acc[mt][nt], 0, 0, 0);
        }
    }
#pragma unroll
    for (int s = 0; s < 3; ++s) {
        short8 bt[3];
#pragma unroll
        for (int nt = 0; nt < 3; ++nt)
            bt[nt] = *(const short8*)(wTbT + (s * 48 + nt * 16 + lane15) * 32 + quad * 8);
        const int tapq = s * 4 + quad;                 // per-quad tap
        const int kyq  = (tapq * 11) >> 5;             // tapq/3 for 0..11
        const int kxq  = tapq - 3 * kyq;
#pragma unroll
        for (int mt = 0; mt < 2; ++mt) {
            const int arowq = (wv * 2 + mt + kyq) * 18 + (lane15 + kxq);
            const int offs  = (tapq < 9) ? (arowq * 40 + 32) : (ZROW * 40);
            const short8 at = *(const short8*)(x1 + offs);
#pragma unroll
            for (int nt = 0; nt < 3; ++nt)
                acc[mt][nt] = __builtin_amdgcn_mfma_f32_16x16x32_bf16(
                    at, bt[nt], acc[mt][nt], 0, 0, 0);
        }
    }

    // ---- dense1 straight from accumulators ----
    // lane owns (pixel = (wv*2+mt)*16 + quad*4+reg, co = nt*16+lane15)
    float a6[6] = {0.f, 0.f, 0.f, 0.f, 0.f, 0.f};
#pragma unroll
    for (int mt = 0; mt < 2; ++mt)
#pragma unroll
        for (int nt = 0; nt < 3; ++nt) {
            const int co = nt * 16 + lane15;
#pragma unroll
            for (int reg = 0; reg < 4; ++reg) {
                const int pixel = (wv * 2 + mt) * 16 + quad * 4 + reg;
                const float* __restrict__ dwp = d1w2 + (pixel * 48 + co) * 6;
                const float a = fmaxf(acc[mt][nt][reg], 0.f);
#pragma unroll
                for (int k = 0; k < 6; ++k)
                    a6[k] = fmaf(a, dwp[k], a6[k]);
            }
        }
    for (int off = 32; off; off >>= 1) {
#pragma unroll
        for (int k = 0; k < 6; ++k) a6[k] += __shfl_down(a6[k], off);
    }
    if (lane == 0) {
#pragma unroll
        for (int k = 0; k < 6; ++k) wsum[wv][k] = a6[k];
    }
    __syncthreads();                                   // B3
    if (t < 6) {
        float s = d1b[t];
#pragma unroll
        for (int w = 0; w < 8; ++w) s += wsum[w][t];
        nodes[n * 6 + t] = fmaxf(s, 0.f);
    }
}

// ---------------------------------------------------------------------------
// Kernel 2: per-node fused edge-MLPs (<=4 incoming, analytic grid adjacency)
// + node MLP + softmax CE. 64-thread blocks to spread across 64 CUs.
// node_id(x,y) = ((x&1)+2*(y&1))*1024 + (x>>1)*32 + (y>>1).
// ---------------------------------------------------------------------------
__global__ __launch_bounds__(64) void k_node(
    const float* __restrict__ nodes, const float* __restrict__ lsv,
    const float* __restrict__ we0, const float* __restrict__ be0,
    const float* __restrict__ we1, const float* __restrict__ be1,
    const float* __restrict__ we2, const float* __restrict__ be2,
    const float* __restrict__ we3, const float* __restrict__ be3,
    const float* __restrict__ wn0, const float* __restrict__ bn0,
    const float* __restrict__ wn1, const float* __restrict__ bn1,
    const float* __restrict__ wn2, const float* __restrict__ bn2,
    const float* __restrict__ wn3, const float* __restrict__ bn3,
    const float* __restrict__ wout, const float* __restrict__ bout,
    float* __restrict__ out, int N)
{
    const int n = blockIdx.x * 64 + threadIdx.x;
    if (n >= N) return;
    const int g = n >> 10, cell = n & 1023;
    const int gi = cell >> 5, gj = cell & 31;
    const int gx = (g & 1) + 2 * gi, gy = (g >> 1) + 2 * gj;

    float self6[6];
#pragma unroll
    for (int i = 0; i < 6; ++i) self6[i] = nodes[n * 6 + i];

    float agg[10] = {0.f,0.f,0.f,0.f,0.f,0.f,0.f,0.f,0.f,0.f};
    const int DX[4] = {0, 0, -1, 1};
    const int DY[4] = {-1, 1, 0, 0};
#pragma unroll
    for (int d = 0; d < 4; ++d) {
        const int x = gx + DX[d], y = gy + DY[d];
        if (x >= 0 && x < 64 && y >= 0 && y < 64) {
            const int mid = ((x & 1) + 2 * (y & 1)) * 1024 + (x >> 1) * 32 + (y >> 1);
            float in13[13];
#pragma unroll
            for (int i = 0; i < 6; ++i) in13[i] = nodes[mid * 6 + i];
#pragma unroll
            for (int i = 0; i < 6; ++i) in13[6 + i] = self6[i];
            in13[12] = 1.f;
            float h0[5], h1[5], h2[5], o[10];
            mlp_layer<13, 5>(in13, we0, be0, h0, true);
            mlp_layer<5, 5>(h0, we1, be1, h1, true);
            mlp_layer<5, 5>(h1, we2, be2, h2, true);
            mlp_layer<5, 10>(h2, we3, be3, o, false);
#pragma unroll
            for (int j = 0; j < 10; ++j) agg[j] += o[j];
        }
    }

    float in17[17];
#pragma unroll
    for (int i = 0; i < 6; ++i)  in17[i]     = self6[i];
#pragma unroll
    for (int i = 0; i < 10; ++i) in17[6 + i] = agg[i];
    in17[16] = 1.f;
    float h0[5], h1[5], h2[5], o[10];
    mlp_layer<17, 5>(in17, wn0, bn0, h0, true);
    mlp_layer<5, 5>(h0, wn1, bn1, h1, true);
    mlp_layer<5, 5>(h1, wn2, bn2, h2, true);
    mlp_layer<5, 10>(h2, wn3, bn3, o, false);

    float l0 = bout[0], l1 = bout[1];
#pragma unroll
    for (int i = 0; i < 10; ++i) {
        l0 = fmaf(o[i], wout[i * 2 + 0], l0);
        l1 = fmaf(o[i], wout[i * 2 + 1], l1);
    }
    const float mx  = fmaxf(l0, l1);
    const float e0  = expf(l0 - mx), e1 = expf(l1 - mx);
    const float lse = mx + logf(e0 + e1);
    const float sv  = lsv[n];
    out[n] = -((1.f - sv) * (l0 - lse) + sv * (l1 - lse));
}

// ---------------------------------------------------------------------------
extern "C" void kernel_launch(void* const* d_in, const int* in_sizes, int n_in,
                              void* d_out, int out_size, void* d_ws, size_t ws_size,
                              hipStream_t stream) {
    (void)n_in; (void)ws_size; (void)in_sizes;
    const float* img = (const float*)d_in[0];
    const float* lab = (const float*)d_in[1];
    const float* msk = (const float*)d_in[2];
    const float* w1  = (const float*)d_in[3];
    const float* b1  = (const float*)d_in[4];
    const float* w2  = (const float*)d_in[5];
    const float* b2  = (const float*)d_in[6];
    const float* d1w = (const float*)d_in[7];
    const float* d1b = (const float*)d_in[8];
    const float* we0 = (const float*)d_in[9],  *be0 = (const float*)d_in[10];
    const float* we1 = (const float*)d_in[11], *be1 = (const float*)d_in[12];
    const float* we2 = (const float*)d_in[13], *be2 = (const float*)d_in[14];
    const float* we3 = (const float*)d_in[15], *be3 = (const float*)d_in[16];
    const float* wn0 = (const float*)d_in[17], *bn0 = (const float*)d_in[18];
    const float* wn1 = (const float*)d_in[19], *bn1 = (const float*)d_in[20];
    const float* wn2 = (const float*)d_in[21], *bn2 = (const float*)d_in[22];
    const float* wn3 = (const float*)d_in[23], *bn3 = (const float*)d_in[24];
    const float* wout = (const float*)d_in[25], *bout = (const float*)d_in[26];
    const int N = out_size;              // 4096 nodes

    float* ws    = (float*)d_ws;
    float* nodes = ws;                                       // N*6 = 24576 f
    float* lsvb  = ws + (size_t)N * 6;                       // N    =  4096 f
    unsigned short* wTb  = (unsigned short*)(ws + 28672);    // 13824 shorts
    unsigned short* wTbT = wTb + NWTB;                       //  4608 shorts
    float* d1w2  = ws + 28672 + (NWTB + NTAIL) / 2;          // 73728 f
    float* out   = (float*)d_out;

    const int prep_n = NWTB + NTAIL + ND1W;
    k_prep<<<(prep_n + 255) / 256, 256, 0, stream>>>(w2, d1w, wTb, wTbT, d1w2);
    k_patch<<<N, 512, 0, stream>>>(img, lab, msk, w1, b1, wTb, wTbT, b2,
                                   d1w2, d1b, nodes, lsvb);
    k_node<<<(N + 63) / 64, 64, 0, stream>>>(nodes, lsvb,
                                             we0, be0, we1, be1, we2, be2,
                                             we3, be3,
                                             wn0, bn0, wn1, bn1, wn2, bn2,
                                             wn3, bn3, wout, bout, out, N);
}

// Round 8
// 216.856 us; speedup vs baseline: 1.8663x; 1.3104x over previous
//
#include <hip/hip_runtime.h>
#include <math.h>

// ---------------------------------------------------------------------------
// H=W=512, CELL=8, P=16, NGH=32; 4096 patches of 16x16, one block per patch.
// conv1 3x3 1->40 fp32 VALU; conv2 3x3 40->40 bf16 MFMA; dense1 from acc regs.
//
// R7 post-mortem: 2.4 GB/dispatch of L2 reads (B-frags re-read by all 8
// waves; d1w2 288 KB re-read by all 4096 blocks) ~= 70 us at L2 BW plus
// exposed latency -> both pipes <26% busy. R8:
//  - B-weights staged to LDS once per block (flat 36.9 KB uint4 copy from a
//    prep-side image already in LDS layout); MFMA loop is pure LDS+MFMA.
//  - dense1 weights bf16 [pixel][co:48][k:8]: one uint4 per segment.
// R5/R2 lessons: no launch-bounds below live set; constant-indexed reg arrays.
// MFMA layouts (HW-verified): A[m=lane&15][k=quad*8+j]; B[k=quad*8+j][n=lane&15];
// C/D col(n)=lane&15, row(m)=quad*4+reg.
// ---------------------------------------------------------------------------

typedef __attribute__((ext_vector_type(8))) short short8;
typedef __attribute__((ext_vector_type(4))) float f32x4;

#define ZROW  324                    // always-zero x1 row (rows 0..323 = 18x18)
#define NWTB  (12 * 4 * 48 * 8)      // 18432 shorts: B image [grp][quad][co:48][j:8]
#define ND1W  (256 * 48 * 8)         // 98304 shorts: dense1 bf16 [pixel][co:48][k:8]

static __device__ __forceinline__ unsigned short f2bf(float x) {
    unsigned int u = __float_as_uint(x);
    u += 0x7FFF + ((u >> 16) & 1);
    return (unsigned short)(u >> 16);
}

static __device__ __forceinline__ float diff_round(float x) {
    const float TP = 6.2831853071795864769f;
    return x - sinf(x * TP) / TP;
}

template<int IN, int OUT>
static __device__ __forceinline__ void mlp_layer(const float* in,
                                                 const float* __restrict__ w,
                                                 const float* __restrict__ b,
                                                 float* out, bool do_relu) {
#pragma unroll
    for (int j = 0; j < OUT; ++j) {
        float a = b[j];
#pragma unroll
        for (int i = 0; i < IN; ++i) a = fmaf(in[i], w[i * OUT + j], a);
        out[j] = do_relu ? fmaxf(a, 0.f) : a;
    }
}

// ---------------------------------------------------------------------------
// Prep: (a) wTbG = B-weight image in EXACTLY the k_patch LDS layout:
//   idx = ((grp*4+quad)*48 + co)*8 + j
//   grp<9 : tap=grp,      ci=quad*8+j   (main K-step, ci 0..31)
//   grp>=9: tap=(grp-9)*4+quad, ci=32+j (tail-packed K-step; tap>=9 -> 0)
// (b) d1wb = dense1 weights bf16, [pixel][co:48][k:8] (k>=6 or co>=40 -> 0).
// ---------------------------------------------------------------------------
__global__ __launch_bounds__(256) void k_prep(const float* __restrict__ w2,
                                              const float* __restrict__ d1w,
                                              unsigned short* __restrict__ wTbG,
                                              unsigned short* __restrict__ d1wb) {
    const int i = blockIdx.x * 256 + threadIdx.x;
    if (i < NWTB) {
        const int j    = i & 7;
        const int co   = (i >> 3) % 48;
        const int qg   = (i >> 3) / 48;
        const int quad = qg & 3;
        const int grp  = qg >> 2;
        float val = 0.f;
        if (grp < 9) {
            if (co < 40) val = w2[(grp * 40 + quad * 8 + j) * 40 + co];
        } else {
            const int tap = (grp - 9) * 4 + quad;
            if (tap < 9 && co < 40) val = w2[(tap * 40 + 32 + j) * 40 + co];
        }
        wTbG[i] = f2bf(val);
    } else if (i < NWTB + ND1W) {
        const int jj = i - NWTB;
        const int k  = jj & 7;
        const int co = (jj >> 3) % 48;
        const int px = (jj >> 3) / 48;
        d1wb[jj] = f2bf((co < 40 && k < 6) ? d1w[(px * 40 + co) * 6 + k] : 0.f);
    }
}

// ---------------------------------------------------------------------------
// Kernel 1: 512 threads/block, one block per patch.
// ph = t>>8 (conv1 channel half), pix = t&255, u=pix>>4, v=pix&15.
// Wave wv (0..7) owns pixel rows wv*2, wv*2+1 in the MFMA phase.
// ---------------------------------------------------------------------------
__global__ __launch_bounds__(512, 4) void k_patch(
    const float* __restrict__ img, const float* __restrict__ lab,
    const float* __restrict__ msk,
    const float* __restrict__ w1, const float* __restrict__ b1,
    const unsigned short* __restrict__ wTbG,
    const float* __restrict__ b2,
    const unsigned short* __restrict__ d1wb, const float* __restrict__ d1b,
    float* __restrict__ nodes, float* __restrict__ lsv)
{
    __shared__ __align__(16) unsigned short x1[325 * 40];   // 26,000 B
    __shared__ __align__(16) unsigned short Bs[NWTB];       // 36,864 B
    __shared__ float p[256];
    __shared__ float red[4][2];
    __shared__ float wsum[8][6];

    const int n = blockIdx.x;
    const int t = threadIdx.x;
    const int g = n >> 10, cell = n & 1023;
    const int gi = cell >> 5, gj = cell & 31;
    const int sx = g & 1, sy = g >> 1;           // SHIFTS (0,0),(1,0),(0,1),(1,1)
    const int gx = sx + 2 * gi, gy = sy + 2 * gj;
    const int px0 = gx * 8 - 4, py0 = gy * 8 - 4;
    const float cid = (float)(gx * 64 + gy);

    const int ph = t >> 8, pix = t & 255;
    const int u = pix >> 4, v = pix & 15;
    const int lane = t & 63, wv = t >> 6;
    const int lane15 = t & 15, quad = (t >> 4) & 3;

    // ---- entry: issue patch global loads (ph==0 half) ----
    float m = -1.f, iv = 0.f, lv = 0.f;
    if (ph == 0) {
        const int r = px0 + u, c = py0 + v;
        if (r >= 0 && r < 512 && c >= 0 && c < 512) {
            m  = msk[r * 512 + c];
            iv = img[r * 512 + c];
            lv = lab[r * 512 + c];
        }
    }

    // ---- stage B-weights into LDS (flat copy, layout matches exactly) ----
    {
        const uint4* src = (const uint4*)wTbG;
        uint4* dst = (uint4*)Bs;
        for (int i = t; i < NWTB / 8; i += 512) dst[i] = src[i];
    }

    // ---- zero x1 borders + ZROW (69 cells * 20 dwords) ----
    {
        unsigned int* x1w = (unsigned int*)x1;
        for (int i = t; i < 69 * 20; i += 512) {
            const int cellI = i / 20, d = i - cellI * 20;
            int cr;
            if      (cellI < 18) cr = cellI;                    // row 0
            else if (cellI < 36) cr = cellI + 288;              // row 17
            else if (cellI < 52) cr = (cellI - 35) * 18;        // col 0, rows 1..16
            else if (cellI < 68) cr = (cellI - 51) * 18 + 17;   // col 17
            else                 cr = ZROW;
            x1w[cr * 20 + d] = 0u;
        }
    }

    // ---- token + label stats (ph==0 waves) ----
    const float f = (m == cid) ? 1.f : 0.f;
    if (ph == 0) {
        p[pix] = iv * f;
        float sf = f, slf = lv * f;
        for (int off = 32; off; off >>= 1) {
            sf  += __shfl_down(sf,  off);
            slf += __shfl_down(slf, off);
        }
        if (lane == 0) { red[wv][0] = sf; red[wv][1] = slf; }
    }
    __syncthreads();                                   // B1

    if (t == 0) {
        const float SF = red[0][0] + red[1][0] + red[2][0] + red[3][0];
        const float SL = red[0][1] + red[1][1] + red[2][1] + red[3][1];
        lsv[n] = diff_round(diff_round(SL / (SF + 1e-8f)));
    }

    // ---- conv1: each thread: its pixel x its 20-channel half ----
    {
        float nbv[9];
#pragma unroll
        for (int ky = 0; ky < 3; ++ky)
#pragma unroll
            for (int kx = 0; kx < 3; ++kx) {
                const int uy = u + ky - 1, vx = v + kx - 1;
                const bool ok = (uy >= 0) && (uy < 16) && (vx >= 0) && (vx < 16);
                nbv[ky * 3 + kx] = ok ? p[uy * 16 + vx] : 0.f;
            }
        float a1[20];
#pragma unroll
        for (int cc = 0; cc < 20; ++cc) a1[cc] = b1[ph * 20 + cc];
#pragma unroll
        for (int k = 0; k < 9; ++k) {
            const float xv = nbv[k];
#pragma unroll
            for (int cc = 0; cc < 20; ++cc)
                a1[cc] = fmaf(xv, w1[k * 40 + ph * 20 + cc], a1[cc]);
        }
        const int row = (u + 1) * 18 + (v + 1);
        unsigned int* x1w = (unsigned int*)x1;
#pragma unroll
        for (int cg = 0; cg < 10; ++cg) {
            const unsigned int lo = f2bf(fmaxf(a1[2 * cg], 0.f));
            const unsigned int hi = f2bf(fmaxf(a1[2 * cg + 1], 0.f));
            x1w[row * 20 + ph * 10 + cg] = lo | (hi << 16);
        }
    }
    __syncthreads();                                   // B2: x1 + Bs ready

    // ---- conv2: 9 main + 3 tail-packed K-steps, all operands from LDS ----
    float bias[3];
#pragma unroll
    for (int nt = 0; nt < 3; ++nt) {
        const int co = nt * 16 + lane15;
        bias[nt] = (co < 40) ? b2[co] : 0.f;
    }
    f32x4 acc[2][3];
#pragma unroll
    for (int mt = 0; mt < 2; ++mt)
#pragma unroll
        for (int nt = 0; nt < 3; ++nt) {
            acc[mt][nt][0] = bias[nt]; acc[mt][nt][1] = bias[nt];
            acc[mt][nt][2] = bias[nt]; acc[mt][nt][3] = bias[nt];
        }

#pragma unroll
    for (int tap = 0; tap < 9; ++tap) {
        const int ky = tap / 3, kx = tap % 3;
        short8 bf[3];
#pragma unroll
        for (int nt = 0; nt < 3; ++nt)
            bf[nt] = *(const short8*)(Bs + ((tap * 4 + quad) * 48 + nt * 16 + lane15) * 8);
#pragma unroll
        for (int mt = 0; mt < 2; ++mt) {
            const int arow = (wv * 2 + mt + ky) * 18 + (lane15 + kx);
            const short8 a0 = *(const short8*)(x1 + arow * 40 + quad * 8);
#pragma unroll
            for (int nt = 0; nt < 3; ++nt)
                acc[mt][nt] = __builtin_amdgcn_mfma_f32_16x16x32_bf16(
                    a0, bf[nt], acc[mt][nt], 0, 0, 0);
        }
    }
#pragma unroll
    for (int s = 0; s < 3; ++s) {
        short8 bt[3];
#pragma unroll
        for (int nt = 0; nt < 3; ++nt)
            bt[nt] = *(const short8*)(Bs + (((9 + s) * 4 + quad) * 48 + nt * 16 + lane15) * 8);
        const int tapq = s * 4 + quad;
        const int kyq  = (tapq * 11) >> 5;             // tapq/3 for 0..11
        const int kxq  = tapq - 3 * kyq;
#pragma unroll
        for (int mt = 0; mt < 2; ++mt) {
            const int arowq = (wv * 2 + mt + kyq) * 18 + (lane15 + kxq);
            const int offs  = (tapq < 9) ? (arowq * 40 + 32) : (ZROW * 40);
            const short8 at = *(const short8*)(x1 + offs);
#pragma unroll
            for (int nt = 0; nt < 3; ++nt)
                acc[mt][nt] = __builtin_amdgcn_mfma_f32_16x16x32_bf16(
                    at, bt[nt], acc[mt][nt], 0, 0, 0);
        }
    }

    // ---- dense1 straight from accumulators; bf16 weights, 1 uint4/segment --
    float a6[6] = {0.f, 0.f, 0.f, 0.f, 0.f, 0.f};
#pragma unroll
    for (int mt = 0; mt < 2; ++mt)
#pragma unroll
        for (int nt = 0; nt < 3; ++nt) {
            const int co = nt * 16 + lane15;
#pragma unroll
            for (int reg = 0; reg < 4; ++reg) {
                const int pixel = (wv * 2 + mt) * 16 + quad * 4 + reg;
                const uint4 wq = *(const uint4*)(d1wb + ((pixel * 48 + co) << 3));
                const float a = fmaxf(acc[mt][nt][reg], 0.f);
                a6[0] = fmaf(a, __uint_as_float(wq.x << 16),          a6[0]);
                a6[1] = fmaf(a, __uint_as_float(wq.x & 0xFFFF0000u),  a6[1]);
                a6[2] = fmaf(a, __uint_as_float(wq.y << 16),          a6[2]);
                a6[3] = fmaf(a, __uint_as_float(wq.y & 0xFFFF0000u),  a6[3]);
                a6[4] = fmaf(a, __uint_as_float(wq.z << 16),          a6[4]);
                a6[5] = fmaf(a, __uint_as_float(wq.z & 0xFFFF0000u),  a6[5]);
            }
        }
    for (int off = 32; off; off >>= 1) {
#pragma unroll
        for (int k = 0; k < 6; ++k) a6[k] += __shfl_down(a6[k], off);
    }
    if (lane == 0) {
#pragma unroll
        for (int k = 0; k < 6; ++k) wsum[wv][k] = a6[k];
    }
    __syncthreads();                                   // B3
    if (t < 6) {
        float s = d1b[t];
#pragma unroll
        for (int w = 0; w < 8; ++w) s += wsum[w][t];
        nodes[n * 6 + t] = fmaxf(s, 0.f);
    }
}

// ---------------------------------------------------------------------------
// Kernel 2: per-node fused edge-MLPs (<=4 incoming, analytic grid adjacency)
// + node MLP + softmax CE.
// node_id(x,y) = ((x&1)+2*(y&1))*1024 + (x>>1)*32 + (y>>1).
// ---------------------------------------------------------------------------
__global__ __launch_bounds__(64) void k_node(
    const float* __restrict__ nodes, const float* __restrict__ lsv,
    const float* __restrict__ we0, const float* __restrict__ be0,
    const float* __restrict__ we1, const float* __restrict__ be1,
    const float* __restrict__ we2, const float* __restrict__ be2,
    const float* __restrict__ we3, const float* __restrict__ be3,
    const float* __restrict__ wn0, const float* __restrict__ bn0,
    const float* __restrict__ wn1, const float* __restrict__ bn1,
    const float* __restrict__ wn2, const float* __restrict__ bn2,
    const float* __restrict__ wn3, const float* __restrict__ bn3,
    const float* __restrict__ wout, const float* __restrict__ bout,
    float* __restrict__ out, int N)
{
    const int n = blockIdx.x * 64 + threadIdx.x;
    if (n >= N) return;
    const int g = n >> 10, cell = n & 1023;
    const int gi = cell >> 5, gj = cell & 31;
    const int gx = (g & 1) + 2 * gi, gy = (g >> 1) + 2 * gj;

    float self6[6];
#pragma unroll
    for (int i = 0; i < 6; ++i) self6[i] = nodes[n * 6 + i];

    float agg[10] = {0.f,0.f,0.f,0.f,0.f,0.f,0.f,0.f,0.f,0.f};
    const int DX[4] = {0, 0, -1, 1};
    const int DY[4] = {-1, 1, 0, 0};
#pragma unroll
    for (int d = 0; d < 4; ++d) {
        const int x = gx + DX[d], y = gy + DY[d];
        if (x >= 0 && x < 64 && y >= 0 && y < 64) {
            const int mid = ((x & 1) + 2 * (y & 1)) * 1024 + (x >> 1) * 32 + (y >> 1);
            float in13[13];
#pragma unroll
            for (int i = 0; i < 6; ++i) in13[i] = nodes[mid * 6 + i];
#pragma unroll
            for (int i = 0; i < 6; ++i) in13[6 + i] = self6[i];
            in13[12] = 1.f;
            float h0[5], h1[5], h2[5], o[10];
            mlp_layer<13, 5>(in13, we0, be0, h0, true);
            mlp_layer<5, 5>(h0, we1, be1, h1, true);
            mlp_layer<5, 5>(h1, we2, be2, h2, true);
            mlp_layer<5, 10>(h2, we3, be3, o, false);
#pragma unroll
            for (int j = 0; j < 10; ++j) agg[j] += o[j];
        }
    }

    float in17[17];
#pragma unroll
    for (int i = 0; i < 6; ++i)  in17[i]     = self6[i];
#pragma unroll
    for (int i = 0; i < 10; ++i) in17[6 + i] = agg[i];
    in17[16] = 1.f;
    float h0[5], h1[5], h2[5], o[10];
    mlp_layer<17, 5>(in17, wn0, bn0, h0, true);
    mlp_layer<5, 5>(h0, wn1, bn1, h1, true);
    mlp_layer<5, 5>(h1, wn2, bn2, h2, true);
    mlp_layer<5, 10>(h2, wn3, bn3, o, false);

    float l0 = bout[0], l1 = bout[1];
#pragma unroll
    for (int i = 0; i < 10; ++i) {
        l0 = fmaf(o[i], wout[i * 2 + 0], l0);
        l1 = fmaf(o[i], wout[i * 2 + 1], l1);
    }
    const float mx  = fmaxf(l0, l1);
    const float e0  = expf(l0 - mx), e1 = expf(l1 - mx);
    const float lse = mx + logf(e0 + e1);
    const float sv  = lsv[n];
    out[n] = -((1.f - sv) * (l0 - lse) + sv * (l1 - lse));
}

// ---------------------------------------------------------------------------
extern "C" void kernel_launch(void* const* d_in, const int* in_sizes, int n_in,
                              void* d_out, int out_size, void* d_ws, size_t ws_size,
                              hipStream_t stream) {
    (void)n_in; (void)ws_size; (void)in_sizes;
    const float* img = (const float*)d_in[0];
    const float* lab = (const float*)d_in[1];
    const float* msk = (const float*)d_in[2];
    const float* w1  = (const float*)d_in[3];
    const float* b1  = (const float*)d_in[4];
    const float* w2  = (const float*)d_in[5];
    const float* b2  = (const float*)d_in[6];
    const float* d1w = (const float*)d_in[7];
    const float* d1b = (const float*)d_in[8];
    const float* we0 = (const float*)d_in[9],  *be0 = (const float*)d_in[10];
    const float* we1 = (const float*)d_in[11], *be1 = (const float*)d_in[12];
    const float* we2 = (const float*)d_in[13], *be2 = (const float*)d_in[14];
    const float* we3 = (const float*)d_in[15], *be3 = (const float*)d_in[16];
    const float* wn0 = (const float*)d_in[17], *bn0 = (const float*)d_in[18];
    const float* wn1 = (const float*)d_in[19], *bn1 = (const float*)d_in[20];
    const float* wn2 = (const float*)d_in[21], *bn2 = (const float*)d_in[22];
    const float* wn3 = (const float*)d_in[23], *bn3 = (const float*)d_in[24];
    const float* wout = (const float*)d_in[25], *bout = (const float*)d_in[26];
    const int N = out_size;              // 4096 nodes

    char* base = (char*)d_ws;
    float* nodes = (float*)base;                             // N*6 floats
    float* lsvb  = (float*)(base + (size_t)N * 6 * 4);       // N floats
    unsigned short* wTbG = (unsigned short*)(base + (size_t)N * 7 * 4);  // 18432
    unsigned short* d1wb = wTbG + NWTB;                      // 98304
    float* out   = (float*)d_out;

    const int prep_n = NWTB + ND1W;
    k_prep<<<(prep_n + 255) / 256, 256, 0, stream>>>(w2, d1w, wTbG, d1wb);
    k_patch<<<N, 512, 0, stream>>>(img, lab, msk, w1, b1, wTbG, b2,
                                   d1wb, d1b, nodes, lsvb);
    k_node<<<(N + 63) / 64, 64, 0, stream>>>(nodes, lsvb,
                                             we0, be0, we1, be1, we2, be2,
                                             we3, be3,
                                             wn0, bn0, wn1, bn1, wn2, bn2,
                                             wn3, bn3, wout, bout, out, N);
}